// Round 10
// baseline (160.365 us; speedup 1.0000x reference)
//
#include <hip/hip_runtime.h>

// R10: 1 block per (n,c) channel (grid 4096), loop over 4 row-tiles of 16x64.
//      Next tile's S0 globals prefetched into REGISTERS under current tile's
//      S2/S4 (issue-early / LDS-write-late). 3 barriers/tile (was 4/tile with
//      4x the blocks). R8 S1/S2 bodies; S4 reverted to R5 1-col/thread b32
//      (R8's b64 S4 created a 4-way bank conflict: rc-stride 576 % 32 == 0).
//   s_in[26 x 80] : own region (no t3 alias) -> col pads written ONCE.
//   t1  [42 x 84] : ST1=84 keeps S2's b128 reads off the dr=2 collision.
//   t3  [42 x 72] : written b128 by S2 (16B-aligned), read b32 by S4 (2-way free).
// LDS = (2080 + 3536 + 3024 + 24)*4 ~= 34.7 KB -> 4 blocks/CU (16 waves).
// Hazard audit (3 barriers): BAR-A S0w->S1 (s_in ready; also fences next-iter
// entry while slow waves sit in S4: S0w touches only s_in, S4 only t3/out);
// BAR-B S1->S2 (t1 ready); BAR-C S2->S4 (t3 ready). Next-iter t1/t3 writes
// are behind next BAR-A/B -> no trailing barrier needed.
#define SIN 80
#define ST1 84
#define ST3 72

typedef float v2f __attribute__((ext_vector_type(2)));

static __device__ __forceinline__ v2f fma2(v2f a, v2f b, v2f c) {
    return __builtin_elementwise_fma(a, b, c);
}
static __device__ __forceinline__ v2f bcast2(float s) { v2f r; r.x = s; r.y = s; return r; }
static __device__ __forceinline__ v2f mk2(float a, float b) { v2f r; r.x = a; r.y = b; return r; }

__global__ __launch_bounds__(256, 4)
void synth_fused(const float* __restrict__ x, const float* __restrict__ bias,
                 const float* __restrict__ fu, const float* __restrict__ fd,
                 float* __restrict__ out)
{
    __shared__ __align__(16) float s_in[2080];   // 26 x 80
    __shared__ __align__(16) float s_t1[3536];   // 42 x 84 + slack (q=5 reads to 3525)
    __shared__ __align__(16) float s_t3[3024];   // 42 x 72
    __shared__ float sfilt[24];

    const int tid = threadIdx.x;
    const int nc  = blockIdx.x;

    if (tid < 24) sfilt[tid] = (tid < 12) ? fu[tid] : fd[tid - 12];
    // column pads: cols 0..4 and 69..79 of all 26 rows — written ONCE
    {
        int idx = tid;
        {   int r = idx >> 4, pc = idx & 15;
            int c = (pc < 5) ? pc : (64 + pc);
            if (idx < 416) s_in[r * SIN + c] = 0.0f; }
        idx = tid + 256;
        if (idx < 416) {
            int r = idx >> 4, pc = idx & 15;
            int c = (pc < 5) ? pc : (64 + pc);
            s_in[r * SIN + c] = 0.0f;
        }
    }
    __syncthreads();                             // sfilt + pads visible

    const float bc = bias[nc & 511];
    const float* __restrict__ xc = x + ((size_t)nc << 12);
    float* __restrict__ oc = out + ((size_t)nc << 12);

    float u0[12], gs[12];
    #pragma unroll
    for (int k = 0; k < 12; ++k) { u0[k] = sfilt[k]; gs[k] = sfilt[23 - k]; }   // gs[k]=fd[11-k]
    v2f gpk[6];
    #pragma unroll
    for (int j = 0; j < 6; ++j) gpk[j] = mk2(gs[2*j], gs[2*j + 1]);
    const float S42 = 4.0f * 1.41421356237309515f;       // x4 up-gain * sqrt2 act-gain
    v2f upk2[6];
    #pragma unroll
    for (int j = 0; j < 6; ++j) upk2[j] = mk2(u0[10 - 2*j] * S42, u0[11 - 2*j] * S42);
    const float bcs = bc * 1.41421356237309515f;

    // ---- prefetch tile 0 into registers ----
    float4 pf0 = make_float4(0.f, 0.f, 0.f, 0.f);
    float4 pf1 = make_float4(0.f, 0.f, 0.f, 0.f);
    {
        int r = tid >> 4, c4 = (tid & 15) << 2;
        int gy = r - 5;
        if ((unsigned)gy < 64u) pf0 = *reinterpret_cast<const float4*>(xc + (gy << 6) + c4);
        int idx = tid + 256;
        if (idx < 416) {
            r = idx >> 4; c4 = (idx & 15) << 2; gy = r - 5;
            if ((unsigned)gy < 64u) pf1 = *reinterpret_cast<const float4*>(xc + (gy << 6) + c4);
        }
    }

    for (int t = 0; t < 4; ++t) {
        const int gy0 = t << 4;

        // ---- S0w: write prefetched registers into s_in (cols 5..68) ----
        {
            int r = tid >> 4, c4 = (tid & 15) << 2;
            float* dst = &s_in[r * SIN + 5 + c4];
            dst[0] = pf0.x; dst[1] = pf0.y; dst[2] = pf0.z; dst[3] = pf0.w;
            int idx = tid + 256;
            if (idx < 416) {
                r = idx >> 4; c4 = (idx & 15) << 2;
                dst = &s_in[r * SIN + 5 + c4];
                dst[0] = pf1.x; dst[1] = pf1.y; dst[2] = pf1.z; dst[3] = pf1.w;
            }
        }
        __syncthreads();                          // BAR-A

        // ---- S1: vertical x2 up, 2 cols/thread b64. 111 thr (g3 0..2, c2 0..36) ----
        if (tid < 111) {
            const int g3 = tid / 37;
            const int c2 = tid - 37 * g3;
            const float* ip = s_in + (7 * g3) * SIN + 2 * c2;
            v2f rv[12];
            #pragma unroll
            for (int j = 0; j < 12; ++j) rv[j] = *reinterpret_cast<const v2f*>(ip + j * SIN);
            float* op = s_t1 + (14 * g3) * ST1 + 2 * c2;
            #pragma unroll
            for (int m = 0; m < 7; ++m) {
                v2f aE = rv[m] * u0[10];
                v2f aO = rv[m] * u0[11];
                #pragma unroll
                for (int j = 1; j < 6; ++j) {
                    aE = fma2(rv[m + j], bcast2(u0[10 - 2*j]), aE);
                    aO = fma2(rv[m + j], bcast2(u0[11 - 2*j]), aO);
                }
                *reinterpret_cast<v2f*>(op + (2*m) * ST1)     = aE;
                *reinterpret_cast<v2f*>(op + (2*m + 1) * ST1) = aO;
            }
        }
        __syncthreads();                          // BAR-B

        // ---- prefetch tile t+1 (issued here; consumed after BAR-A of next iter) ----
        if (t < 3) {
            const int gy0n = (t + 1) << 4;
            int r = tid >> 4, c4 = (tid & 15) << 2;
            int gy = gy0n - 5 + r;
            pf0 = make_float4(0.f, 0.f, 0.f, 0.f);
            if ((unsigned)gy < 64u) pf0 = *reinterpret_cast<const float4*>(xc + (gy << 6) + c4);
            int idx = tid + 256;
            pf1 = make_float4(0.f, 0.f, 0.f, 0.f);
            if (idx < 416) {
                r = idx >> 4; c4 = (idx & 15) << 2; gy = gy0n - 5 + r;
                if ((unsigned)gy < 64u) pf1 = *reinterpret_cast<const float4*>(xc + (gy << 6) + c4);
            }
        }

        // ---- S2: fused H-up + lrelu/clamp + H-down. 252 thr (r 0..41, q 0..5) ----
        if (tid < 252) {
            const int r = tid / 6;
            const int q = tid - 6 * r;
            const float* t1r = s_t1 + r * ST1 + 12 * q;
            float w[22];
            #pragma unroll
            for (int j = 0; j < 5; ++j) {              // 5 x b128 (16B-aligned)
                float4 v4 = *reinterpret_cast<const float4*>(t1r + 4 * j);
                w[4*j] = v4.x; w[4*j+1] = v4.y; w[4*j+2] = v4.z; w[4*j+3] = v4.w;
            }
            { v2f v2 = *reinterpret_cast<const v2f*>(t1r + 20); w[20] = v2.x; w[21] = v2.y; }
            const v2f bc2 = bcast2(bcs);
            v2f t2p[17];
            #pragma unroll
            for (int i = 0; i < 17; ++i) {
                v2f acc = bc2;
                #pragma unroll
                for (int j = 0; j < 6; ++j)
                    acc = fma2(upk2[j], bcast2(w[i + j]), acc);
                v2f mx = __builtin_elementwise_max(acc, acc * 0.2f);
                t2p[i] = mk2(__builtin_amdgcn_fmed3f(mx.x, -256.0f, 256.0f),
                             __builtin_amdgcn_fmed3f(mx.y, -256.0f, 256.0f));
            }
            float* t3r = s_t3 + r * ST3 + 12 * q;
            #pragma unroll
            for (int i = 0; i < 3; ++i) {
                float4 o4;
                float* op = &o4.x;
                #pragma unroll
                for (int s = 0; s < 4; ++s) {
                    const int oi = 4 * i + s;
                    v2f acc = gpk[0] * t2p[oi];
                    #pragma unroll
                    for (int j = 1; j < 6; ++j) acc = fma2(gpk[j], t2p[oi + j], acc);
                    op[s] = acc.x + acc.y;
                }
                *reinterpret_cast<float4*>(t3r + 4 * i) = o4;
            }
        }
        __syncthreads();                          // BAR-C

        // ---- S4: vertical /2 down, 1 col/thread b32 (conflict-free), 256 thr ----
        {
            const int c  = tid & 63;
            const int rc = tid >> 6;
            const float* t3c = s_t3 + (rc << 3) * ST3 + c;
            float wv[18];
            #pragma unroll
            for (int j = 0; j < 18; ++j) wv[j] = t3c[j * ST3];
            float* op = oc + ((size_t)(gy0 + (rc << 2)) << 6) + c;
            #pragma unroll
            for (int i = 0; i < 4; ++i) {
                float acc = gs[0] * wv[2*i];
                #pragma unroll
                for (int k = 1; k < 12; ++k) acc = fmaf(gs[k], wv[2*i + k], acc);
                op[(size_t)(i << 6)] = acc;
            }
        }
        // no trailing barrier: next S0w writes only s_in (disjoint from t3/out);
        // next BAR-A fences before any t1/t3 producer runs.
    }
}

extern "C" void kernel_launch(void* const* d_in, const int* in_sizes, int n_in,
                              void* d_out, int out_size, void* d_ws, size_t ws_size,
                              hipStream_t stream) {
    const float* x    = (const float*)d_in[0];
    const float* bias = (const float*)d_in[1];
    const float* fu   = (const float*)d_in[2];
    const float* fd   = (const float*)d_in[3];
    float* out        = (float*)d_out;

    dim3 grid(8 * 512);       // one block per (n,c) channel; 4 tiles looped inside
    dim3 block(256);
    hipLaunchKernelGGL(synth_fused, grid, block, 0, stream, x, bias, fu, fd, out);
}

// Round 11
// 156.396 us; speedup vs baseline: 1.0254x; 1.0254x over previous
//
#include <hip/hip_runtime.h>

// Tile: 16 output rows x 64 output cols; 4 tiles per (n,c); grid 16384.
// R11: R9 base (75.2us). S2 broadcasts rewritten as shufflevector(pair,pair,k,k)
//      -> op_sel-foldable into v_pk_fma_f32 (targets hidden v_mov pairs that
//      bcast2() may have been costing). S4 reverted to R5 1-col/thread b32
//      (R9's b64 S4 made a 4-way conflict: rc-stride 576 % 32 == 0).
//   S0 load -> S1 V-up(x2) -> S2 [H-up + act + H-down] fused -> S4 V-down + store.
//   s_in[26 x 80] : input rows gy0-5..gy0+20, cols -5..74 zero-padded   (bufA)
//   t1  [42 x 84] : vertical x2 up, cols 0..73 valid (ST1=84: S2 b128
//                   reads off the dr=2 bank collision of stride 80)     (bufB)
//   t3  [42 x 72] : H-up+act+H-down result, cols 0..63 valid            (bufA)
// LDS = (3024 + 3536 + 24)*4 = 26.3 KB -> 6 blocks/CU.
#define SIN 80
#define ST1 84
#define ST3 72

typedef float v2f __attribute__((ext_vector_type(2)));

static __device__ __forceinline__ v2f fma2(v2f a, v2f b, v2f c) {
    return __builtin_elementwise_fma(a, b, c);
}
static __device__ __forceinline__ v2f bcast2(float s) { v2f r; r.x = s; r.y = s; return r; }
static __device__ __forceinline__ v2f mk2(float a, float b) { v2f r; r.x = a; r.y = b; return r; }

__global__ __launch_bounds__(256, 4)
void synth_fused(const float* __restrict__ x, const float* __restrict__ bias,
                 const float* __restrict__ fu, const float* __restrict__ fd,
                 float* __restrict__ out)
{
    __shared__ __align__(16) float bufA[3024];   // s_in 26x80=2080 | t3 42x72=3024
    __shared__ __align__(16) float bufB[3536];   // t1 42x84=3528 + slack (q=5 reads to 3525)
    __shared__ float sfilt[24];
    float* const s_in = bufA;
    float* const s_t3 = bufA;
    float* const s_t1 = bufB;

    const int tid  = threadIdx.x;
    const int bx   = blockIdx.x;
    const int tile = bx & 3;
    const int nc   = bx >> 2;
    const int gy0  = tile << 4;

    if (tid < 24) sfilt[tid] = (tid < 12) ? fu[tid] : fd[tid - 12];
    const float bc = bias[nc & 511];
    const float* __restrict__ xc = x + ((size_t)nc << 12);

    // ---- S0: load 26 rows x 64 cols (float4 global, coalesced) + zero pad ----
    #pragma unroll
    for (int it = 0; it < 2; ++it) {
        int idx = tid + it * 256;
        if (idx < 416) {                         // 26 rows * 16 float4
            int r  = idx >> 4;
            int c4 = (idx & 15) << 2;
            int gy = gy0 - 5 + r;
            float4 v = make_float4(0.f, 0.f, 0.f, 0.f);
            if ((unsigned)gy < 64u)
                v = *reinterpret_cast<const float4*>(xc + (gy << 6) + c4);
            float* dst = s_in + r * SIN + 5 + c4;
            dst[0] = v.x; dst[1] = v.y; dst[2] = v.z; dst[3] = v.w;
        }
    }
    #pragma unroll
    for (int it = 0; it < 2; ++it) {                 // 26*16 pad slots (cols 0..4, 69..79)
        int idx = tid + it * 256;
        if (idx < 416) {
            int r  = idx >> 4;
            int pc = idx & 15;
            int c  = (pc < 5) ? pc : (64 + pc);
            s_in[r * SIN + c] = 0.0f;
        }
    }
    __syncthreads();

    // filter registers
    float u0[12], gs[12];
    #pragma unroll
    for (int k = 0; k < 12; ++k) { u0[k] = sfilt[k]; gs[k] = sfilt[23 - k]; }   // gs[k]=fd[11-k]
    v2f gpk[6];
    #pragma unroll
    for (int j = 0; j < 6; ++j) gpk[j] = mk2(gs[2*j], gs[2*j + 1]);

    // ---- S1: vertical x2 up, 2 cols/thread b64. 111 thr (g3 0..2, c2 0..36) ----
    // {t1[2m][2c2..+1], t1[2m+1][...]} = sum_j u0[10/11-2j] * s_in[7g3+m+j][2c2..+1]
    if (tid < 111) {
        const int g3 = tid / 37;
        const int c2 = tid - 37 * g3;
        const float* ip = s_in + (7 * g3) * SIN + 2 * c2;
        v2f rv[12];
        #pragma unroll
        for (int j = 0; j < 12; ++j) rv[j] = *reinterpret_cast<const v2f*>(ip + j * SIN);
        float* op = s_t1 + (14 * g3) * ST1 + 2 * c2;
        #pragma unroll
        for (int m = 0; m < 7; ++m) {
            v2f aE = rv[m] * u0[10];
            v2f aO = rv[m] * u0[11];
            #pragma unroll
            for (int j = 1; j < 6; ++j) {
                aE = fma2(rv[m + j], bcast2(u0[10 - 2*j]), aE);
                aO = fma2(rv[m + j], bcast2(u0[11 - 2*j]), aO);
            }
            *reinterpret_cast<v2f*>(op + (2*m) * ST1)     = aE;
            *reinterpret_cast<v2f*>(op + (2*m + 1) * ST1) = aO;
        }
    }
    __syncthreads();

    // fold x4 up-gain AND sqrt2 act-gain into H-up taps; sqrt2 into bias
    const float S42 = 4.0f * 1.41421356237309515f;
    v2f upk2[6];
    #pragma unroll
    for (int j = 0; j < 6; ++j) upk2[j] = mk2(u0[10 - 2*j] * S42, u0[11 - 2*j] * S42);
    const float bcs = bc * 1.41421356237309515f;

    // ---- S2: fused H-up + lrelu/clamp + H-down. 252 thr (r 0..41, q 0..5) ----
    // wp[k] = {t1[r][12q+2k], t1[r][12q+2k+1]};  broadcast of element s via
    // shufflevector(wp[s>>1], wp[s>>1], s&1, s&1)  (op_sel-foldable, no movs).
    // t2p[i] = act( sum_j upk2[j]*bcast(w[i+j]) + {bcs,bcs} ),  i 0..16
    // t3[r][12q+oi] = hadd( sum_j gpk[j]*t2p[oi+j] ),  oi 0..11
    // q=5: t1 cols >=74 garbage -> feeds only t3 cols >=64 (pad, never read).
    if (tid < 252) {
        const int r = tid / 6;
        const int q = tid - 6 * r;
        const float* t1r = s_t1 + r * ST1 + 12 * q;
        v2f wp[11];
        #pragma unroll
        for (int j = 0; j < 5; ++j) {                  // 5 x b128 (16B-aligned: 84r+12q)
            float4 v4 = *reinterpret_cast<const float4*>(t1r + 4 * j);
            wp[2*j]     = mk2(v4.x, v4.y);
            wp[2*j + 1] = mk2(v4.z, v4.w);
        }
        wp[10] = *reinterpret_cast<const v2f*>(t1r + 20);
        const v2f bc2 = bcast2(bcs);
        v2f t2p[17];
        #pragma unroll
        for (int i = 0; i < 17; ++i) {
            v2f acc = bc2;
            #pragma unroll
            for (int j = 0; j < 6; ++j) {
                const int s = i + j;
                const v2f wb = (s & 1)
                    ? __builtin_shufflevector(wp[s >> 1], wp[s >> 1], 1, 1)
                    : __builtin_shufflevector(wp[s >> 1], wp[s >> 1], 0, 0);
                acc = fma2(upk2[j], wb, acc);
            }
            v2f mx = __builtin_elementwise_max(acc, acc * 0.2f);
            t2p[i] = mk2(__builtin_amdgcn_fmed3f(mx.x, -256.0f, 256.0f),
                         __builtin_amdgcn_fmed3f(mx.y, -256.0f, 256.0f));
        }
        float* t3r = s_t3 + r * ST3 + 12 * q;
        #pragma unroll
        for (int i = 0; i < 3; ++i) {
            float4 o4;
            float* op = &o4.x;
            #pragma unroll
            for (int s = 0; s < 4; ++s) {
                const int oi = 4 * i + s;
                v2f acc = gpk[0] * t2p[oi];
                #pragma unroll
                for (int j = 1; j < 6; ++j) acc = fma2(gpk[j], t2p[oi + j], acc);
                op[s] = acc.x + acc.y;
            }
            *reinterpret_cast<float4*>(t3r + 4 * i) = o4;
        }
    }
    __syncthreads();

    // ---- S4: vertical /2 down, 1 col/thread b32 (conflict-free), 256 thr ----
    // out rows gy0+4rc..+3 at col c; reads t3 rows 8rc..8rc+17.
    {
        const int c  = tid & 63;
        const int rc = tid >> 6;
        const float* t3c = s_t3 + (rc << 3) * ST3 + c;
        float wv[18];
        #pragma unroll
        for (int j = 0; j < 18; ++j) wv[j] = t3c[j * ST3];
        float* op = out + ((size_t)nc << 12) + ((size_t)(gy0 + (rc << 2)) << 6) + c;
        #pragma unroll
        for (int i = 0; i < 4; ++i) {
            float acc = gs[0] * wv[2*i];
            #pragma unroll
            for (int k = 1; k < 12; ++k) acc = fmaf(gs[k], wv[2*i + k], acc);
            op[(size_t)(i << 6)] = acc;
        }
    }
}

extern "C" void kernel_launch(void* const* d_in, const int* in_sizes, int n_in,
                              void* d_out, int out_size, void* d_ws, size_t ws_size,
                              hipStream_t stream) {
    const float* x    = (const float*)d_in[0];
    const float* bias = (const float*)d_in[1];
    const float* fu   = (const float*)d_in[2];
    const float* fd   = (const float*)d_in[3];
    float* out        = (float*)d_out;

    dim3 grid(8 * 512 * 4);   // (n*c) x 4 row-tiles of 16x64
    dim3 block(256);
    hipLaunchKernelGGL(synth_fused, grid, block, 0, stream, x, bias, fu, fd, out);
}